// Round 2
// baseline (118.622 us; speedup 1.0000x reference)
//
#include <hip/hip_runtime.h>

// BoxFilter: out = 9x9 box SUM of x with zero padding (truncated edge windows)
// == diff_y(diff_x(cumsum_H(x), 4).cumsum_W, 4).
//
// R2 structure: barrier-free, LDS-free. One wave per 8-row strip of a full
// 1024-wide row. Each lane owns 4 strided column chunks (col = 256*j + 4*lane)
// so every global load/store is a perfectly coalesced 1KB wave transaction.
// Vertical 9-tap: register running sum, advance = +row(i+5) -row(i-4)
// (re-load of the drop row hits L1/L2). Horizontal 9-tap: in-register via
// lane-rotate shuffles; wave spans the whole row, so lane-boundary halos are
// the image's zero padding, and inter-chunk halos are published into the
// rotate via a cndmask select (lane 63 publishes prev chunk for the up-rotate,
// lane 0 publishes next chunk for the down-rotate).

#define RR 4
#define HH 1024
#define WW 1024
#define STRIP 8
#define BLOCK 256
#define WPB (BLOCK / 64)

__device__ __forceinline__ float shl(float a, int src) { return __shfl(a, src, 64); }

// rotate with boundary publish: lane l receives (pub? alt : v) from lane src(l)
__device__ __forceinline__ float4 shpub(bool pub, const float4 alt, const float4 v, int src) {
    float4 s;
    s.x = shl(pub ? alt.x : v.x, src);
    s.y = shl(pub ? alt.y : v.y, src);
    s.z = shl(pub ? alt.z : v.z, src);
    s.w = shl(pub ? alt.w : v.w, src);
    return s;
}

// 9-tap horizontal sliding sum: window cols c-4..c+4 for outputs c..c+3
__device__ __forceinline__ float4 hsum9(const float4 L, const float4 v, const float4 R) {
    float4 o;
    o.x = L.x + L.y + L.z + L.w + v.x + v.y + v.z + v.w + R.x;
    o.y = o.x - L.x + R.y;
    o.z = o.y - L.y + R.z;
    o.w = o.z - L.z + R.w;
    return o;
}

__device__ __forceinline__ void acc4(float4& a, const float4 b, const float4 c) {
    // a += b - c
    a.x += b.x - c.x; a.y += b.y - c.y; a.z += b.z - c.z; a.w += b.w - c.w;
}

__global__ __launch_bounds__(BLOCK) void box9_kernel(const float* __restrict__ x,
                                                     float* __restrict__ out) {
    const int lane  = threadIdx.x & 63;
    const int wid   = threadIdx.x >> 6;
    const int strip = blockIdx.x * WPB + wid;
    const int spi   = HH / STRIP; // strips per image
    const int img   = strip / spi;
    const int r0    = (strip - img * spi) * STRIP;
    const size_t ioff = (size_t)img * HH * WW;
    const float* __restrict__ xi = x + ioff;
    float* __restrict__ oi       = out + ioff;
    const int c = 4 * lane;

    const int upSrc = (lane + 63) & 63;
    const int dnSrc = (lane + 1) & 63;
    const bool top = (lane == 63); // publishes prev chunk into up-rotate
    const bool bot = (lane == 0);  // publishes next chunk into down-rotate
    const float4 z4 = {0.f, 0.f, 0.f, 0.f};

    // init vertical sums for row r0: rows r0-4 .. r0+4 (zero outside)
    float4 v0 = z4, v1 = z4, v2 = z4, v3 = z4;
#pragma unroll
    for (int k = 0; k < 2 * RR + 1; ++k) {
        const int r = r0 - RR + k;
        if (r >= 0 && r < HH) {
            const float* p = xi + (size_t)r * WW + c;
            float4 t;
            t = *(const float4*)(p);       v0.x += t.x; v0.y += t.y; v0.z += t.z; v0.w += t.w;
            t = *(const float4*)(p + 256); v1.x += t.x; v1.y += t.y; v1.z += t.z; v1.w += t.w;
            t = *(const float4*)(p + 512); v2.x += t.x; v2.y += t.y; v2.z += t.z; v2.w += t.w;
            t = *(const float4*)(p + 768); v3.x += t.x; v3.y += t.y; v3.z += t.z; v3.w += t.w;
        }
    }

#pragma unroll 2
    for (int i = r0; i < r0 + STRIP; ++i) {
        // issue next-row loads early (hide under shuffles/VALU below)
        const int rn = i + RR + 1;
        const int rd = i - RR;
        float4 n0 = z4, n1 = z4, n2 = z4, n3 = z4;
        float4 d0 = z4, d1 = z4, d2 = z4, d3 = z4;
        if (rn < HH) {
            const float* p = xi + (size_t)rn * WW + c;
            n0 = *(const float4*)(p);
            n1 = *(const float4*)(p + 256);
            n2 = *(const float4*)(p + 512);
            n3 = *(const float4*)(p + 768);
        }
        if (rd >= 0) {
            const float* p = xi + (size_t)rd * WW + c;
            d0 = *(const float4*)(p);
            d1 = *(const float4*)(p + 256);
            d2 = *(const float4*)(p + 512);
            d3 = *(const float4*)(p + 768);
        }

        // horizontal 9-tap for row i (v holds vertical sums of row i)
        float* po = oi + (size_t)i * WW + c;
        {
            const float4 L = shpub(top, z4, v0, upSrc);
            const float4 R = shpub(bot, v1, v0, dnSrc);
            *(float4*)(po) = hsum9(L, v0, R);
        }
        {
            const float4 L = shpub(top, v0, v1, upSrc);
            const float4 R = shpub(bot, v2, v1, dnSrc);
            *(float4*)(po + 256) = hsum9(L, v1, R);
        }
        {
            const float4 L = shpub(top, v1, v2, upSrc);
            const float4 R = shpub(bot, v3, v2, dnSrc);
            *(float4*)(po + 512) = hsum9(L, v2, R);
        }
        {
            const float4 L = shpub(top, v2, v3, upSrc);
            const float4 R = shpub(bot, z4, v3, dnSrc);
            *(float4*)(po + 768) = hsum9(L, v3, R);
        }

        // advance vertical window to row i+1
        acc4(v0, n0, d0);
        acc4(v1, n1, d1);
        acc4(v2, n2, d2);
        acc4(v3, n3, d3);
    }
}

extern "C" void kernel_launch(void* const* d_in, const int* in_sizes, int n_in,
                              void* d_out, int out_size, void* d_ws, size_t ws_size,
                              hipStream_t stream) {
    const float* x = (const float*)d_in[0];
    float* out     = (float*)d_out;
    const int nimg = in_sizes[0] / (HH * WW);     // 48
    const int strips = nimg * (HH / STRIP);       // 6144
    dim3 grid(strips / WPB, 1, 1);                // 1536 blocks
    box9_kernel<<<grid, BLOCK, 0, stream>>>(x, out);
}

// Round 4
// 102.605 us; speedup vs baseline: 1.1561x; 1.1561x over previous
//
#include <hip/hip_runtime.h>

// BoxFilter: out = 9x9 box SUM of x with zero padding == reference
// diff_y(diff_x(cumsum_H(x),4).cumsum_W,4). fp32 in/out, 48 x 1024x1024.
//
// R4 = R3 with the NT-store compile fix (native ext_vector_type for the
// builtin). Structure:
//  - TILE=32, GROUP=4 -> grid 1536 blocks (6/CU), LDS 16.5KB -> ~24 waves/CU
//  - raw s_barrier with lgkmcnt-only wait: global row prefetches stay in
//    flight ACROSS barriers (T4: never drain vmcnt in the main loop)
//  - next-group HBM rows (nx) prefetched into regs one group ahead
//  - nontemporal stores: output never re-read; keep L2/L3 for input halo
//  - drop-row loads (dp) re-read rows fetched <=13 rows ago (L1/L2 hit)

#define RR 4
#define HH 1024
#define WW 1024
#define BLOCK 256
#define TILE 32
#define GROUP 4
#define NG (TILE / GROUP)
#define LDSW (WW + 2 * RR) // 1032

typedef float f32x4 __attribute__((ext_vector_type(4)));

__device__ __forceinline__ float4 zero4() {
    float4 z; z.x = 0.f; z.y = 0.f; z.z = 0.f; z.w = 0.f; return z;
}
__device__ __forceinline__ void add4(float4& a, const float4 b) {
    a.x += b.x; a.y += b.y; a.z += b.z; a.w += b.w;
}
__device__ __forceinline__ void accdiff(float4& a, const float4 b, const float4 c) {
    a.x += b.x - c.x; a.y += b.y - c.y; a.z += b.z - c.z; a.w += b.w - c.w;
}
__device__ __forceinline__ void nt_store4(float* p, const float4 o) {
    f32x4 t; t.x = o.x; t.y = o.y; t.z = o.z; t.w = o.w;
    __builtin_nontemporal_store(t, (f32x4*)p);
}

__global__ __launch_bounds__(BLOCK, 6) void box9_kernel(const float* __restrict__ x,
                                                        float* __restrict__ out) {
    const int tid = threadIdx.x;
    const int img = blockIdx.y;
    const int r0  = blockIdx.x * TILE;
    const size_t ioff = (size_t)img * HH * WW;
    const float* __restrict__ xi = x + ioff;
    float* __restrict__ oi       = out + ioff;
    const int c = 4 * tid;

    __shared__ float vlds[GROUP][LDSW];

    // constant zero column halos (cols -4..-1 and 1024..1027); written once,
    // first read is after the first barrier.
    if (tid < GROUP) {
        vlds[tid][0] = 0.f; vlds[tid][1] = 0.f; vlds[tid][2] = 0.f; vlds[tid][3] = 0.f;
        vlds[tid][LDSW - 4] = 0.f; vlds[tid][LDSW - 3] = 0.f;
        vlds[tid][LDSW - 2] = 0.f; vlds[tid][LDSW - 1] = 0.f;
    }

    // v = vertical 9-sum at row r0 (rows r0-4..r0+4; r0+4 <= 996 always valid)
    float4 v = zero4();
#pragma unroll
    for (int k = -RR; k <= RR; ++k) {
        const int r = r0 + k;
        if (r >= 0) add4(v, *(const float4*)(xi + (size_t)r * WW + c));
    }
    // prefetch group 0's "next" rows r0+5..r0+8 (always in range: r0 <= 992)
    float4 nx[GROUP];
#pragma unroll
    for (int k = 0; k < GROUP; ++k)
        nx[k] = *(const float4*)(xi + (size_t)(r0 + RR + 1 + k) * WW + c);

    for (int g = 0; g < NG; ++g) {
        const int b = r0 + g * GROUP;

        // ---- phase 1: issue next-group prefetch, publish v-rows, advance v
        float4 nnx[GROUP], dp[GROUP];
#pragma unroll
        for (int k = 0; k < GROUP; ++k) { // rows b+9..b+12 for group g+1
            const int rn = b + 2 * RR + 1 + k;
            nnx[k] = (rn < HH) ? *(const float4*)(xi + (size_t)rn * WW + c) : zero4();
        }
#pragma unroll
        for (int k = 0; k < GROUP; ++k) { // drop rows b-4..b-1 (L1/L2 hit)
            const int rd = b - RR + k;
            dp[k] = (rd >= 0) ? *(const float4*)(xi + (size_t)rd * WW + c) : zero4();
        }
#pragma unroll
        for (int k = 0; k < GROUP; ++k) {
            *(float4*)(&vlds[k][4 + c]) = v;
            accdiff(v, nx[k], dp[k]);
        }
        asm volatile("s_waitcnt lgkmcnt(0)" ::: "memory"); // LDS visible; vmcnt NOT drained
        __builtin_amdgcn_s_barrier();

        // ---- phase 2: horizontal 9-tap sliding sum from LDS, NT store
#pragma unroll
        for (int k = 0; k < GROUP; ++k) {
            const float4 a0 = *(const float4*)(&vlds[k][c]);
            const float4 a1 = *(const float4*)(&vlds[k][c + 4]);
            const float4 a2 = *(const float4*)(&vlds[k][c + 8]);
            float4 o;
            o.x = a0.x + a0.y + a0.z + a0.w + a1.x + a1.y + a1.z + a1.w + a2.x;
            o.y = o.x - a0.x + a2.y;
            o.z = o.y - a0.y + a2.z;
            o.w = o.z - a0.z + a2.w;
            nt_store4(oi + (size_t)(b + k) * WW + c, o);
        }
        asm volatile("s_waitcnt lgkmcnt(0)" ::: "memory"); // my ds_reads already consumed; cheap
        __builtin_amdgcn_s_barrier();                      // protect vlds overwrite next group

#pragma unroll
        for (int k = 0; k < GROUP; ++k) nx[k] = nnx[k];
    }
}

extern "C" void kernel_launch(void* const* d_in, const int* in_sizes, int n_in,
                              void* d_out, int out_size, void* d_ws, size_t ws_size,
                              hipStream_t stream) {
    const float* x = (const float*)d_in[0];
    float* out     = (float*)d_out;
    const int nimg = in_sizes[0] / (HH * WW); // 48
    dim3 grid(HH / TILE, nimg, 1);            // (32, 48) = 1536 blocks
    box9_kernel<<<grid, BLOCK, 0, stream>>>(x, out);
}